// Round 1
// 363.391 us; speedup vs baseline: 1.1409x; 1.1409x over previous
//
#include <hip/hip_runtime.h>
#include <hip/hip_bf16.h>

typedef unsigned short u16;
typedef unsigned int u32;
typedef __bf16 bf16x8 __attribute__((ext_vector_type(8)));
typedef float floatx4 __attribute__((ext_vector_type(4)));
typedef __hip_bfloat16 bf;

constexpr int BK  = 32;          // K-elems per LDS tile (one 16x16x32 MFMA k-slab)
constexpr int TSZ = 128 * BK;    // elems per tile buffer = 8 KiB; LINEAR layout
                                 // (global_load_lds writes base+lane*16 — no pad
                                 //  allowed, m104/m173). m97 measured 874 TF with
                                 //  this exact linear [128][32] layout.

__device__ __forceinline__ __bf16 f2b(float f) {
    __hip_bfloat16 h = __float2bfloat16(f);
    return *reinterpret_cast<__bf16*>(&h);
}
__device__ __forceinline__ bf16x8 ld8f(const float* p) {
    float4 a = ((const float4*)p)[0];
    float4 b = ((const float4*)p)[1];
    bf16x8 r;
    r[0] = f2b(a.x); r[1] = f2b(a.y); r[2] = f2b(a.z); r[3] = f2b(a.w);
    r[4] = f2b(b.x); r[5] = f2b(b.y); r[6] = f2b(b.z); r[7] = f2b(b.w);
    return r;
}

__device__ __forceinline__ void storev(float* p, float v) { *p = v; }
__device__ __forceinline__ void storev(bf* p, float v)    { *p = __float2bfloat16(v); }

// async 16-B global->LDS; per-wave: lane l lands at (wave-uniform base)+l*16.
// Our thread->LDS map is tid*16 = wave*1024 + lane*16, which conforms.
__device__ __forceinline__ void gl16(const bf* g, u16* l) {
    __builtin_amdgcn_global_load_lds(
        (const __attribute__((address_space(1))) void*)g,
        (__attribute__((address_space(3))) void*)l, 16, 0, 0);
}

// one 128x128x32 tile's MFMA work; linear LDS stride = BK
__device__ __forceinline__ void mfma_tile(const u16* Ac, const u16* Bc,
                                          floatx4 (&acc)[4][4],
                                          int wm, int wn, int fr, int fk)
{
    bf16x8 af[4], bv[4];
#pragma unroll
    for (int q = 0; q < 4; q++)
        af[q] = *(const bf16x8*)&Ac[(wm + q * 16 + fr) * BK + fk];
#pragma unroll
    for (int j = 0; j < 4; j++)
        bv[j] = *(const bf16x8*)&Bc[(wn + j * 16 + fr) * BK + fk];
#pragma unroll
    for (int q = 0; q < 4; q++)
#pragma unroll
        for (int j = 0; j < 4; j++)
            acc[q][j] = __builtin_amdgcn_mfma_f32_16x16x32_bf16(
                af[q], bv[j], acc[q][j], 0, 0, 0);
}

// ============================================================================
// NT GEMM core, m97 structure: C[m,n] = scale * sum_k A[m,k]*B[n,k].
// 128x128 tile, BK=32, 256 thr = 4 waves, 4x4 mfma_f32_16x16x32_bf16/wave.
// Staging is pure global_load_lds width=16 (4 instrs/thread/K-step), LDS
// linear double-buffered, ONE barrier per K-step (the barrier's vmcnt(0)
// drain doubles as the staging wait).  bf16 operands only — fp32 inputs are
// pre-converted once (see cvt kernels) so no VALU cvt in the hot loop.
// Requires K % 32 == 0, K >= 64.
// ============================================================================
template <typename OutT>
__device__ __forceinline__ void gemm_core(
    const bf* __restrict__ A, const bf* __restrict__ B, OutT* __restrict__ C,
    int K, int N, int m_blk, int n_blk, float scale, u16* As, u16* Bs)
{
    const int tid  = threadIdx.x;
    const int wave = tid >> 6;
    const int lane = tid & 63;

    // staging map: thread t covers 16 B at LDS byte t*16 (rows 0..63) and
    // 4096+t*16 (rows 64..127); row = t>>2, k-off = (t&3)*8 elems.
    const int r0 = tid >> 2;
    const int cc = (tid & 3) * 8;
    const bf* Ag0 = A + (long)(m_blk + r0) * K + cc;
    const bf* Ag1 = Ag0 + (long)64 * K;
    const bf* Bg0 = B + (long)(n_blk + r0) * K + cc;
    const bf* Bg1 = Bg0 + (long)64 * K;
    u16* const la0 = As + tid * 8;
    u16* const la1 = As + 64 * BK + tid * 8;
    u16* const lb0 = Bs + tid * 8;
    u16* const lb1 = Bs + 64 * BK + tid * 8;

    floatx4 acc[4][4];
#pragma unroll
    for (int q = 0; q < 4; q++)
#pragma unroll
        for (int j = 0; j < 4; j++) acc[q][j] = (floatx4){0.f, 0.f, 0.f, 0.f};

    const int wm = (wave >> 1) * 64;
    const int wn = (wave & 1) * 64;
    const int fr = lane & 15;
    const int fk = (lane >> 4) * 8;

    const int T = K >> 5;

    // prologue: stage tile 0 into buffer 0
    gl16(Ag0, la0); gl16(Ag1, la1);
    gl16(Bg0, lb0); gl16(Bg1, lb1);
    __syncthreads();

    for (int kt = 1; kt < T; ++kt) {
        const int cur = (kt - 1) & 1;
        const int nxt = kt & 1;
        const long ko = (long)kt * BK;
        // issue next tile's async loads into the other buffer...
        gl16(Ag0 + ko, la0 + nxt * TSZ); gl16(Ag1 + ko, la1 + nxt * TSZ);
        gl16(Bg0 + ko, lb0 + nxt * TSZ); gl16(Bg1 + ko, lb1 + nxt * TSZ);
        // ...while computing the current one
        mfma_tile(As + cur * TSZ, Bs + cur * TSZ, acc, wm, wn, fr, fk);
        __syncthreads();   // drains vmcnt (staging done) + guards reuse of cur
    }
    mfma_tile(As + ((T - 1) & 1) * TSZ, Bs + ((T - 1) & 1) * TSZ,
              acc, wm, wn, fr, fk);

    // C-write: C/D layout col=lane&15, row=(lane>>4)*4+reg  [m89/m91]
    const int c_col0 = n_blk + wn + fr;
    const int c_row0 = m_blk + wm + (lane >> 4) * 4;
#pragma unroll
    for (int q = 0; q < 4; q++)
#pragma unroll
        for (int r = 0; r < 4; r++) {
            const long row = c_row0 + q * 16 + r;
#pragma unroll
            for (int j = 0; j < 4; j++)
                storev(&C[row * N + c_col0 + j * 16], acc[q][j][r] * scale);
        }
}

// generic z-batched wrapper (bf16 x bf16 -> OutT)
template <typename OutT>
__global__ __launch_bounds__(256)
void gemm_z(const bf* __restrict__ A, const bf* __restrict__ B,
            OutT* __restrict__ C, int K, int N,
            long sA, long sB, long sC, float scale)
{
    __shared__ __align__(16) u16 As[2 * TSZ];
    __shared__ __align__(16) u16 Bs[2 * TSZ];
    gemm_core(A + blockIdx.z * sA, B + blockIdx.z * sB, C + blockIdx.z * sC,
              K, N, blockIdx.y * 128, blockIdx.x * 128, scale, As, Bs);
}

// Q and K projections fused into one launch (z selects operand set)
__global__ __launch_bounds__(256)
void gemm_qk(const bf* __restrict__ xb, const bf* __restrict__ memb,
             const bf* __restrict__ Wqb, const bf* __restrict__ Wkb,
             bf* __restrict__ Q, bf* __restrict__ Kp, float qscale)
{
    __shared__ __align__(16) u16 As[2 * TSZ];
    __shared__ __align__(16) u16 Bs[2 * TSZ];
    const int z = blockIdx.z;
    gemm_core(z ? memb : xb, z ? Wkb : Wqb, z ? Kp : Q,
              1024, 1024, blockIdx.y * 128, blockIdx.x * 128,
              z ? 1.f : qscale, As, Bs);
}

// ============================================================================
// fp32 -> bf16 conversion pre-pass (vectorized, memory-bound, ~20 us total).
// Same RTN conversion the old kernel did per-GEMM-load, so numerics identical.
// ============================================================================
__global__ __launch_bounds__(256)
void cvt2(const float* __restrict__ a, const float* __restrict__ b,
          bf* __restrict__ da, bf* __restrict__ db, long n)
{
    const float* s = blockIdx.z ? b : a;
    bf* d = blockIdx.z ? db : da;
    const long stride = (long)gridDim.x * 256;
    for (long i = (long)blockIdx.x * 256 + threadIdx.x; i * 8 < n; i += stride)
        *(bf16x8*)(d + i * 8) = ld8f(s + i * 8);
}

__global__ __launch_bounds__(256)
void cvt_w(const float* __restrict__ w0, const float* __restrict__ w1,
           const float* __restrict__ w2, const float* __restrict__ w3,
           bf* __restrict__ d)
{
    const int z = blockIdx.z;
    const float* s = (z == 0) ? w0 : (z == 1) ? w1 : (z == 2) ? w2 : w3;
    bf* dz = d + (long)z * (1 << 20);
    const long i = ((long)blockIdx.x * 256 + threadIdx.x) * 8;  // exact cover
    *(bf16x8*)(dz + i) = ld8f(s + i);
}

// ============================================================================
// In-place bf16 row softmax over 2048 logits; one block per row.
// ============================================================================
__global__ __launch_bounds__(256)
void softmax_rows_2048(bf* __restrict__ X)
{
    const long row = blockIdx.x;
    const int t = threadIdx.x;
    const int wave = t >> 6, lane = t & 63;
    __shared__ float red[8];

    float v[8];
    float m = -1e30f;
#pragma unroll
    for (int i = 0; i < 8; i++) {
        v[i] = __bfloat162float(X[row * 2048 + t + i * 256]);
        m = fmaxf(m, v[i]);
    }
#pragma unroll
    for (int o = 32; o > 0; o >>= 1) m = fmaxf(m, __shfl_xor(m, o, 64));
    if (lane == 0) red[wave] = m;
    __syncthreads();
    m = fmaxf(fmaxf(red[0], red[1]), fmaxf(red[2], red[3]));

    float s = 0.f;
#pragma unroll
    for (int i = 0; i < 8; i++) { v[i] = __expf(v[i] - m); s += v[i]; }
#pragma unroll
    for (int o = 32; o > 0; o >>= 1) s += __shfl_xor(s, o, 64);
    if (lane == 0) red[4 + wave] = s;
    __syncthreads();
    s = red[4] + red[5] + red[6] + red[7];

    const float inv = 1.f / s;
#pragma unroll
    for (int i = 0; i < 8; i++)
        X[row * 2048 + t + i * 256] = __float2bfloat16(v[i] * inv);
}

// ============================================================================
// Pipeline (8 dispatches), all GEMMs bf16 x bf16 via global_load_lds staging:
//   1. cvt2:   x,mem fp32 -> xb,memb bf16     (live in d_out until logits)
//   2. cvt_w:  Wq,Wk,Wv,Wo -> bf16            (ws chunk 3, alive to the end)
//   3. gemm_qk (z=2, 1024 blk)                 xb/memb -> Q,Kp
//   4. Vt proj (z=4,  512 blk)                 Vt[b][e,m]=Wvb[e,:].memb[b][m,:]
//   5. logits  (z=4, 1024 blk) -> Lg bf16 [4][2048][2048] in d_out
//        (xb/memb dead; Lg = exactly out_size = 32 MiB -> no g-loop anymore,
//         every launch is full-machine)
//   6. softmax (8192 blk) in-place on Lg
//   7. AO      (z=4,  512 blk) -> AO (aliases Q; Q dead after logits)
//   8. final   (512 blk)                       out fp32 (Lg dead, not read)
// Workspace: Q/AO 16 + Kp 16 + Vt 16 + Wb 8 = 56 MiB (< previous 64 MiB).
// ============================================================================
extern "C" void kernel_launch(void* const* d_in, const int* in_sizes, int n_in,
                              void* d_out, int out_size, void* d_ws, size_t ws_size,
                              hipStream_t stream)
{
    const float* x   = (const float*)d_in[0];  // [4,2048,1024] fp32
    const float* mem = (const float*)d_in[1];
    const float* Wq  = (const float*)d_in[2];  // [1024,1024] fp32 [out,in]
    const float* Wk  = (const float*)d_in[3];
    const float* Wv  = (const float*)d_in[4];
    const float* Wo  = (const float*)d_in[5];

    constexpr int  B = 4, L = 2048, D = 1024;
    constexpr long LD = (long)L * D;   // 2 Mi elems
    constexpr long LL = (long)L * L;   // 4 Mi elems
    constexpr size_t CH = 1u << 24;    // 16 MiB

    char* ws = (char*)d_ws;
    bf* Q   = (bf*)(ws + 0 * CH);      // [4][2048][1024]; AO aliases later
    bf* Kp  = (bf*)(ws + 1 * CH);      // [4][2048][1024]
    bf* Vt  = (bf*)(ws + 2 * CH);      // [4][1024][2048]
    bf* Wb  = (bf*)(ws + 3 * CH);      // 4x [1024][1024] bf16 weights
    bf* Wqb = Wb;
    bf* Wkb = Wb + (long)(1 << 20);
    bf* Wvb = Wb + (long)2 * (1 << 20);
    bf* Wob = Wb + (long)3 * (1 << 20);
    bf* AO  = Q;

    bf* xb   = (bf*)d_out;             // 16 MiB  (dead after step 4)
    bf* memb = (bf*)d_out + B * LD;    // 16 MiB  (dead after step 4)
    bf* Lg   = (bf*)d_out;             // [4][2048][2048] = 32 MiB (steps 5-7)

    dim3 blk(256);
    const float qscale = 0.03125f;     // 1024^-0.5

    // 1-2. one-shot bf16 conversion of all fp32 operands
    cvt2<<<dim3(1024, 1, 2), blk, 0, stream>>>(x, mem, xb, memb, B * LD);
    cvt_w<<<dim3(512, 1, 4), blk, 0, stream>>>(Wq, Wk, Wv, Wo, Wb);

    // 3. Q = x@Wq^T * s, K = mem@Wk^T
    gemm_qk<<<dim3(D / 128, B * L / 128, 2), blk, 0, stream>>>(
        xb, memb, Wqb, Wkb, Q, Kp, qscale);

    // 4. Vt[b] = Wvb (.) memb[b]^T : M=D, N=L, K=D
    gemm_z<bf><<<dim3(L / 128, D / 128, B), blk, 0, stream>>>(
        Wvb, memb, Vt, D, L, 0, LD, (long)D * L, 1.f);

    // 5. logits[b][q,m] = Q[b][q,:].Kp[b][m,:] : M=N=L, K=D  (overwrites xb/memb)
    gemm_z<bf><<<dim3(L / 128, L / 128, B), blk, 0, stream>>>(
        Q, Kp, Lg, D, L, LD, LD, LL, 1.f);

    // 6. softmax in place
    softmax_rows_2048<<<dim3(B * L), blk, 0, stream>>>(Lg);

    // 7. AO[b][q,e] = P[b][q,:].Vt[b][e,:] : M=L, N=D, K=L
    gemm_z<bf><<<dim3(D / 128, L / 128, B), blk, 0, stream>>>(
        Lg, Vt, AO, L, D, LL, (long)D * L, LD, 1.f);

    // 8. out = AO @ Wob^T : M=B*L, N=D, K=D  (Lg dead; out fully overwritten)
    gemm_z<float><<<dim3(D / 128, B * L / 128, 1), blk, 0, stream>>>(
        AO, Wob, (float*)d_out, D, D, 0, 0, 0, 1.f);
}

// Round 2
// 293.887 us; speedup vs baseline: 1.4107x; 1.2365x over previous
//
#include <hip/hip_runtime.h>
#include <hip/hip_bf16.h>

typedef unsigned short u16;
typedef __bf16 bf16x8 __attribute__((ext_vector_type(8)));
typedef float floatx4 __attribute__((ext_vector_type(4)));
typedef __hip_bfloat16 bf;

__device__ __forceinline__ __bf16 f2b(float f) {
    __hip_bfloat16 h = __float2bfloat16(f);
    return *reinterpret_cast<__bf16*>(&h);
}
__device__ __forceinline__ bf16x8 ld8f(const float* p) {
    float4 a = ((const float4*)p)[0];
    float4 b = ((const float4*)p)[1];
    bf16x8 r;
    r[0] = f2b(a.x); r[1] = f2b(a.y); r[2] = f2b(a.z); r[3] = f2b(a.w);
    r[4] = f2b(b.x); r[5] = f2b(b.y); r[6] = f2b(b.z); r[7] = f2b(b.w);
    return r;
}
__device__ __forceinline__ void storev(float* p, float v) { *p = v; }
__device__ __forceinline__ void storev(bf* p, float v)    { *p = __float2bfloat16(v); }

// async 16-B global->LDS (dest = wave-uniform base + lane*16; our dest map
// tid*16 conforms: wave*1024 + lane*16)
__device__ __forceinline__ void gl16(const bf* g, u16* l) {
    __builtin_amdgcn_global_load_lds(
        (const __attribute__((address_space(1))) void*)g,
        (__attribute__((address_space(3))) void*)l, 16, 0, 0);
}

// ============================================================================
// 8-phase NT GEMM: C[m,n] = scale * sum_k A[m,k]*B[n,k]
// Tile BM=128 x BN=256, BK=64 (K-tile). 512 thr = 8 waves (2M x 4N), per-wave
// output 64x64 = 4x4 16x16 frags. LDS 96 KiB: 2 K-tile buffers, each
// {A:2 regions x [64][64], B:2 regions x [128][64]}, region-major so
// global_load_lds' linear dest matches.
//
// Region staircase (derived from the m201 template, all hazards checked):
//   buf0 reads: A0@ph1, B1@ph2, A1@ph3, B0@ph8(next tile-pair's B0)
//   buf1 reads: B0@ph4, A0@ph5, B1@ph6, A1@ph7
//   staging (1 region/phase, overwrites exactly 1 phase after last read):
//     ph1:B0(t+2)->buf0  ph2:A0(t+2)  ph3:B1(t+2)  ph4:A1(t+2)
//     ph5:B0(t+3)->buf1  ph6:A0(t+3)  ph7:B1(t+3)  ph8:A1(t+3)
//   waits: s_waitcnt vmcnt(4) at END of ph4 and ph8 only (3 half-tiles in
//   flight); every region's read is covered by a wait+barrier before it.
// MFMA quadrants: ph2..5 cover tile t, ph6,7,8 + next-ph1 cover tile t+1
// (iter-0 ph1 skipped; epilogue finishes tile T-1's last quadrant).
// LDS k-swizzle: LDS(row, kl) holds X[grow][kl ^ ((row&7)<<3)] — applied on
// the pre-swizzled GLOBAL source (gl16 dest stays linear) and on ds_read.
// Requires K % 128 == 0 (K in {1024, 2048}).
// ============================================================================

#define FENCE asm volatile("" ::: "memory")
#define BARx  __builtin_amdgcn_s_barrier()
#define LGKM0 asm volatile("s_waitcnt lgkmcnt(0)" ::: "memory")
#define VM4   asm volatile("s_waitcnt vmcnt(4)" ::: "memory")
#define VM0   asm volatile("s_waitcnt vmcnt(0)" ::: "memory")

#define ST_A(h, kt, Ab) \
    gl16(Asrc + (long)((h) * 32) * K + (long)(kt) * 64, (Ab) + (h) * 4096 + tid * 8)
#define ST_B(c, kt, Bb) do { \
    gl16(Bsrc + (long)((c) * 32) * K + (long)(kt) * 64, (Bb) + (c) * 8192 + tid * 8); \
    gl16(Bsrc + (long)((c) * 32 + 128) * K + (long)(kt) * 64, (Bb) + (c) * 8192 + 4096 + tid * 8); \
} while (0)

#define RD_A(dst, h, Ab) do { _Pragma("unroll") \
    for (int q_ = 0; q_ < 2; q_++) { \
        const u16* p_ = (Ab) + ((h) * 64 + wg * 32 + q_ * 16 + fr) * 64; \
        dst[q_ * 2 + 0] = *(const bf16x8*)(p_ + kl0); \
        dst[q_ * 2 + 1] = *(const bf16x8*)(p_ + kl1); \
    } } while (0)

#define RD_B(dst, c, Bb) do { _Pragma("unroll") \
    for (int j_ = 0; j_ < 2; j_++) { \
        const u16* p_ = (Bb) + ((c) * 128 + w4 * 32 + j_ * 16 + fr) * 64; \
        dst[j_ * 2 + 0] = *(const bf16x8*)(p_ + kl0); \
        dst[j_ * 2 + 1] = *(const bf16x8*)(p_ + kl1); \
    } } while (0)

#define QMM(h, c, av, bv) do { _Pragma("unroll") \
    for (int q_ = 0; q_ < 2; q_++) _Pragma("unroll") \
    for (int j_ = 0; j_ < 2; j_++) _Pragma("unroll") \
    for (int kk_ = 0; kk_ < 2; kk_++) \
        acc[(h) * 2 + q_][(c) * 2 + j_] = __builtin_amdgcn_mfma_f32_16x16x32_bf16( \
            av[q_ * 2 + kk_], bv[j_ * 2 + kk_], acc[(h) * 2 + q_][(c) * 2 + j_], 0, 0, 0); \
} while (0)

template <typename OutT>
__device__ __forceinline__ void gemm8_core(
    const bf* __restrict__ A, const bf* __restrict__ B, OutT* __restrict__ C,
    int K, int N, int m_blk, int n_blk, float scale, u16* lds)
{
    const int tid  = threadIdx.x;
    const int w    = tid >> 6, lane = tid & 63;
    const int wg   = w >> 2, w4 = w & 3;          // wave grid 2M x 4N
    const int fr   = lane & 15, kg = lane >> 4;

    // LDS geometry (elems): buf0 {A:8192, B:16384}, buf1 likewise
    u16* const A0b = lds;
    u16* const B0b = lds + 8192;
    u16* const A1b = lds + 24576;
    u16* const B1b = lds + 32768;

    // read-side swizzled k offsets (kl1 = kl0 ^ 32 holds under the swizzle)
    const int kl0 = (kg * 8) ^ ((fr & 7) << 3);
    const int kl1 = kl0 ^ 32;

    // staging constants: thread t covers LDS row (t>>3), 16B chunk (t&7);
    // source col pre-swizzled with the same involution keyed on row&7
    const int sr  = tid >> 3;                      // 0..63
    const int scs = ((tid & 7) * 8) ^ ((sr & 7) << 3);
    const bf* Asrc = A + (long)(m_blk + (tid >> 8) * 64 + (sr & 31)) * K + scs;
    const bf* Bsrc = B + (long)(n_blk + (tid >> 8) * 64 + (sr & 31)) * K + scs;

    floatx4 acc[4][4];
#pragma unroll
    for (int i = 0; i < 4; i++)
#pragma unroll
        for (int j = 0; j < 4; j++) acc[i][j] = (floatx4){0.f, 0.f, 0.f, 0.f};

    bf16x8 a0[4], a1[4], b0a[4], b0b[4], b1[4];

    const int T     = K >> 6;    // K-tiles, even
    const int iters = T >> 1;

    // prologue: stage tiles 0 (buf0) and 1 (buf1), drain, prime b0a = B0(t0)
    ST_B(0, 0, B0b); ST_A(0, 0, A0b); ST_B(1, 0, B0b); ST_A(1, 0, A0b);
    ST_B(0, 1, B1b); ST_A(0, 1, A1b); ST_B(1, 1, B1b); ST_A(1, 1, A1b);
    VM0; BARx;
    RD_B(b0a, 0, B0b);
    LGKM0; BARx;

    for (int it = 0; it < iters; ++it) {
        const int t   = it * 2;
        const int ts0 = (t + 2 < T) ? t + 2 : 0;   // clamped: data unused
        const int ts1 = (t + 3 < T) ? t + 3 : 0;

        // ph1: rd A0(t); stage B0(t+2)->buf0; mfma (A1,B0)(t-1)
        RD_A(a0, 0, A0b);  ST_B(0, ts0, B0b);  FENCE; BARx; LGKM0;
        __builtin_amdgcn_s_setprio(1);
        if (it) QMM(1, 0, a1, b0b);
        __builtin_amdgcn_s_setprio(0);
        FENCE; BARx;

        // ph2: rd B1(t); stage A0(t+2); mfma (A0,B0)(t)
        RD_B(b1, 1, B0b);  ST_A(0, ts0, A0b);  FENCE; BARx; LGKM0;
        __builtin_amdgcn_s_setprio(1); QMM(0, 0, a0, b0a);
        __builtin_amdgcn_s_setprio(0); FENCE; BARx;

        // ph3: rd A1(t); stage B1(t+2); mfma (A0,B1)(t)
        RD_A(a1, 1, A0b);  ST_B(1, ts0, B0b);  FENCE; BARx; LGKM0;
        __builtin_amdgcn_s_setprio(1); QMM(0, 1, a0, b1);
        __builtin_amdgcn_s_setprio(0); FENCE; BARx;

        // ph4: rd B0(t+1); stage A1(t+2); mfma (A1,B1)(t); vmcnt(4)
        RD_B(b0b, 0, B1b); ST_A(1, ts0, A0b);  FENCE; BARx; LGKM0;
        __builtin_amdgcn_s_setprio(1); QMM(1, 1, a1, b1);
        __builtin_amdgcn_s_setprio(0); VM4; FENCE; BARx;

        // ph5: rd A0(t+1); stage B0(t+3)->buf1; mfma (A1,B0)(t)
        RD_A(a0, 0, A1b);  ST_B(0, ts1, B1b);  FENCE; BARx; LGKM0;
        __builtin_amdgcn_s_setprio(1); QMM(1, 0, a1, b0a);
        __builtin_amdgcn_s_setprio(0); FENCE; BARx;

        // ph6: rd B1(t+1); stage A0(t+3); mfma (A0,B0)(t+1)
        RD_B(b1, 1, B1b);  ST_A(0, ts1, A1b);  FENCE; BARx; LGKM0;
        __builtin_amdgcn_s_setprio(1); QMM(0, 0, a0, b0b);
        __builtin_amdgcn_s_setprio(0); FENCE; BARx;

        // ph7: rd A1(t+1); stage B1(t+3); mfma (A0,B1)(t+1)
        RD_A(a1, 1, A1b);  ST_B(1, ts1, B1b);  FENCE; BARx; LGKM0;
        __builtin_amdgcn_s_setprio(1); QMM(0, 1, a0, b1);
        __builtin_amdgcn_s_setprio(0); FENCE; BARx;

        // ph8: rd B0(t+2) from buf0; stage A1(t+3); mfma (A1,B1)(t+1); vmcnt(4)
        RD_B(b0a, 0, B0b); ST_A(1, ts1, A1b);  FENCE; BARx; LGKM0;
        __builtin_amdgcn_s_setprio(1); QMM(1, 1, a1, b1);
        __builtin_amdgcn_s_setprio(0); VM4; FENCE; BARx;
    }
    // epilogue: last quadrant (A1,B0) of tile T-1 (regs: a1@ph7, b0b@ph4)
    QMM(1, 0, a1, b0b);

    // C-write: C/D layout col=lane&15, row=(lane>>4)*4+reg  [m89/m91]
    const long c_col0 = n_blk + w4 * 64 + fr;
    const long c_row0 = m_blk + wg * 64 + (lane >> 4) * 4;
#pragma unroll
    for (int rf = 0; rf < 4; rf++)
#pragma unroll
        for (int r = 0; r < 4; r++) {
            const long row = c_row0 + rf * 16 + r;
#pragma unroll
            for (int cf = 0; cf < 4; cf++)
                storev(&C[row * N + c_col0 + cf * 16], acc[rf][cf][r] * scale);
        }
}

template <typename OutT>
__global__ __launch_bounds__(512)
void gemm8(const bf* __restrict__ A, const bf* __restrict__ B,
           OutT* __restrict__ C, int K, int N,
           long sA, long sB, long sC, float scale)
{
    __shared__ __align__(16) u16 lds[49152];   // 96 KiB
    gemm8_core(A + blockIdx.z * sA, B + blockIdx.z * sB, C + blockIdx.z * sC,
               K, N, blockIdx.y * 128, blockIdx.x * 256, scale, lds);
}

__global__ __launch_bounds__(512)
void gemm8_qk(const bf* __restrict__ xb, const bf* __restrict__ memb,
              const bf* __restrict__ Wqb, const bf* __restrict__ Wkb,
              bf* __restrict__ Q, bf* __restrict__ Kp, float qscale)
{
    __shared__ __align__(16) u16 lds[49152];
    const int z = blockIdx.z;
    gemm8_core(z ? memb : xb, z ? Wkb : Wqb, z ? Kp : Q, 1024, 1024,
               blockIdx.y * 128, blockIdx.x * 256, z ? 1.f : qscale, lds);
}

// ============================================================================
// fp32 -> bf16 conversion pre-pass (memory-bound, ~20 us total)
// ============================================================================
__global__ __launch_bounds__(256)
void cvt2(const float* __restrict__ a, const float* __restrict__ b,
          bf* __restrict__ da, bf* __restrict__ db, long n)
{
    const float* s = blockIdx.z ? b : a;
    bf* d = blockIdx.z ? db : da;
    const long stride = (long)gridDim.x * 256;
    for (long i = (long)blockIdx.x * 256 + threadIdx.x; i * 8 < n; i += stride)
        *(bf16x8*)(d + i * 8) = ld8f(s + i * 8);
}

__global__ __launch_bounds__(256)
void cvt_w(const float* __restrict__ w0, const float* __restrict__ w1,
           const float* __restrict__ w2, const float* __restrict__ w3,
           bf* __restrict__ d)
{
    const int z = blockIdx.z;
    const float* s = (z == 0) ? w0 : (z == 1) ? w1 : (z == 2) ? w2 : w3;
    bf* dz = d + (long)z * (1 << 20);
    const long i = ((long)blockIdx.x * 256 + threadIdx.x) * 8;
    *(bf16x8*)(dz + i) = ld8f(s + i);
}

// ============================================================================
// In-place bf16 row softmax over 2048 logits; one block per row.
// ============================================================================
__global__ __launch_bounds__(256)
void softmax_rows_2048(bf* __restrict__ X)
{
    const long row = blockIdx.x;
    const int t = threadIdx.x;
    const int wave = t >> 6, lane = t & 63;
    __shared__ float red[8];

    float v[8];
    float m = -1e30f;
#pragma unroll
    for (int i = 0; i < 8; i++) {
        v[i] = __bfloat162float(X[row * 2048 + t + i * 256]);
        m = fmaxf(m, v[i]);
    }
#pragma unroll
    for (int o = 32; o > 0; o >>= 1) m = fmaxf(m, __shfl_xor(m, o, 64));
    if (lane == 0) red[wave] = m;
    __syncthreads();
    m = fmaxf(fmaxf(red[0], red[1]), fmaxf(red[2], red[3]));

    float s = 0.f;
#pragma unroll
    for (int i = 0; i < 8; i++) { v[i] = __expf(v[i] - m); s += v[i]; }
#pragma unroll
    for (int o = 32; o > 0; o >>= 1) s += __shfl_xor(s, o, 64);
    if (lane == 0) red[4 + wave] = s;
    __syncthreads();
    s = red[4] + red[5] + red[6] + red[7];

    const float inv = 1.f / s;
#pragma unroll
    for (int i = 0; i < 8; i++)
        X[row * 2048 + t + i * 256] = __float2bfloat16(v[i] * inv);
}

// ============================================================================
// Pipeline (8 dispatches), all GEMMs 8-phase 128x256 (every grid >= 256 blk):
//   1. cvt2   x,mem -> xb,memb bf16 (in d_out, dead after Vt/logits)
//   2. cvt_w  weights -> bf16 (ws chunk 3)
//   3. qk     grid(4,64,2)=512
//   4. Vt     grid(8,8,4)=256     Vt[b][e,m] = Wvb[e,:].memb[b][m,:]
//   5. logits grid(8,16,4)=512 -> Lg bf16 [4][2048][2048] in d_out
//   6. softmax 8192 blk in place
//   7. AO     grid(4,16,4)=256 (aliases Q; K=2048)
//   8. final  grid(4,64,1)=256 -> out fp32
// Workspace: Q/AO 16 + Kp 16 + Vt 16 + Wb 8 = 56 MiB.
// ============================================================================
extern "C" void kernel_launch(void* const* d_in, const int* in_sizes, int n_in,
                              void* d_out, int out_size, void* d_ws, size_t ws_size,
                              hipStream_t stream)
{
    const float* x   = (const float*)d_in[0];
    const float* mem = (const float*)d_in[1];
    const float* Wq  = (const float*)d_in[2];
    const float* Wk  = (const float*)d_in[3];
    const float* Wv  = (const float*)d_in[4];
    const float* Wo  = (const float*)d_in[5];

    constexpr int  B = 4, L = 2048, D = 1024;
    constexpr long LD = (long)L * D;
    constexpr long LL = (long)L * L;
    constexpr size_t CH = 1u << 24;

    char* ws = (char*)d_ws;
    bf* Q   = (bf*)(ws + 0 * CH);
    bf* Kp  = (bf*)(ws + 1 * CH);
    bf* Vt  = (bf*)(ws + 2 * CH);
    bf* Wb  = (bf*)(ws + 3 * CH);
    bf* Wqb = Wb;
    bf* Wkb = Wb + (long)(1 << 20);
    bf* Wvb = Wb + (long)2 * (1 << 20);
    bf* Wob = Wb + (long)3 * (1 << 20);
    bf* AO  = Q;

    bf* xb   = (bf*)d_out;
    bf* memb = (bf*)d_out + B * LD;
    bf* Lg   = (bf*)d_out;

    const float qscale = 0.03125f;

    cvt2<<<dim3(1024, 1, 2), dim3(256), 0, stream>>>(x, mem, xb, memb, B * LD);
    cvt_w<<<dim3(512, 1, 4), dim3(256), 0, stream>>>(Wq, Wk, Wv, Wo, Wb);

    // 3. Q = x@Wq^T * s, K = mem@Wk^T : M=8192, N=1024, K=1024
    gemm8_qk<<<dim3(4, 64, 2), dim3(512), 0, stream>>>(
        xb, memb, Wqb, Wkb, Q, Kp, qscale);

    // 4. Vt[b] = Wvb (.) memb[b]^T : M=1024, N=2048, K=1024
    gemm8<bf><<<dim3(8, 8, 4), dim3(512), 0, stream>>>(
        Wvb, memb, Vt, D, L, 0, LD, (long)D * L, 1.f);

    // 5. logits[b][q,m] = Q[b][q,:].Kp[b][m,:] : M=2048, N=2048, K=1024
    gemm8<bf><<<dim3(8, 16, 4), dim3(512), 0, stream>>>(
        Q, Kp, Lg, D, L, LD, LD, LL, 1.f);

    // 6. softmax in place
    softmax_rows_2048<<<dim3(B * L), dim3(256), 0, stream>>>(Lg);

    // 7. AO[b][q,e] = P[b][q,:].Vt[b][e,:] : M=2048, N=1024, K=2048
    gemm8<bf><<<dim3(4, 16, 4), dim3(512), 0, stream>>>(
        Lg, Vt, AO, L, D, LL, (long)D * L, LD, 1.f);

    // 8. out = AO @ Wob^T : M=8192, N=1024, K=1024
    gemm8<float><<<dim3(4, 64, 1), dim3(512), 0, stream>>>(
        AO, Wob, (float*)d_out, D, D, 0, 0, 0, 1.f);
}